// Round 1
// baseline (1101.406 us; speedup 1.0000x reference)
//
#include <hip/hip_runtime.h>
#include <hip/hip_bf16.h>

// Problem constants (from reference): B=4, S=1024, D=1024, H=16, HD=64
#define BB 4
#define SS 1024
#define DD 1024
#define HH 16
#define HD 64
#define MM (BB * SS)      // 4096 rows
#define LN_EPS 1e-12f

// ---------------------------------------------------------------------------
// GEMM: C[M,N] = A[M,K] @ W[K,N] + bias[N]    (M=4096, N=K=1024)
// 64x64 tile, BK=16, 256 threads, 4x4 outputs/thread, fp32.
// ---------------------------------------------------------------------------
#define TM 64
#define TN 64
#define TK 16

__global__ __launch_bounds__(256) void gemm_bias(
    const float* __restrict__ A, const float* __restrict__ W,
    const float* __restrict__ bias, float* __restrict__ C)
{
    const int N = DD, K = DD;
    __shared__ float As[TK][TM];   // staged transposed: As[k][m]
    __shared__ float Ws[TK][TN];   // Ws[k][n]

    const int tid = threadIdx.x;
    const int tx = tid & 15;       // col group 0..15
    const int ty = tid >> 4;       // row group 0..15
    const int bm = blockIdx.x * TM;
    const int bn = blockIdx.y * TN;

    float acc[4][4] = {};

    for (int k0 = 0; k0 < K; k0 += TK) {
        // A tile: rows bm..bm+63, cols k0..k0+15  (coalesced float4 per thread)
        {
            const int row = tid >> 2;            // 0..63
            const int kc  = (tid & 3) * 4;       // 0,4,8,12
            const float4 a4 = *(const float4*)(&A[(size_t)(bm + row) * K + k0 + kc]);
            As[kc + 0][row] = a4.x;
            As[kc + 1][row] = a4.y;
            As[kc + 2][row] = a4.z;
            As[kc + 3][row] = a4.w;
        }
        // W tile: rows k0..k0+15, cols bn..bn+63
        {
            const int kr = tid >> 4;             // 0..15
            const int nc = (tid & 15) * 4;       // 0..60
            const float4 w4 = *(const float4*)(&W[(size_t)(k0 + kr) * N + bn + nc]);
            *(float4*)&Ws[kr][nc] = w4;
        }
        __syncthreads();

        #pragma unroll
        for (int kk = 0; kk < TK; ++kk) {
            const float4 a4 = *(const float4*)&As[kk][ty * 4];
            const float4 w4 = *(const float4*)&Ws[kk][tx * 4];
            const float a[4] = {a4.x, a4.y, a4.z, a4.w};
            const float w[4] = {w4.x, w4.y, w4.z, w4.w};
            #pragma unroll
            for (int i = 0; i < 4; ++i)
                #pragma unroll
                for (int j = 0; j < 4; ++j)
                    acc[i][j] += a[i] * w[j];
        }
        __syncthreads();
    }

    #pragma unroll
    for (int i = 0; i < 4; ++i) {
        const int row = bm + ty * 4 + i;
        const int col = bn + tx * 4;
        float4 o;
        o.x = acc[i][0] + bias[col + 0];
        o.y = acc[i][1] + bias[col + 1];
        o.z = acc[i][2] + bias[col + 2];
        o.w = acc[i][3] + bias[col + 3];
        *(float4*)&C[(size_t)row * N + col] = o;
    }
}

// ---------------------------------------------------------------------------
// Flash-style attention. One block (256 thr) per (b, h, 32-query tile).
// Q,K,V stored [B,S,D] with head h at columns h*64..h*64+63.
// ---------------------------------------------------------------------------
#define QB 32
#define KBL 32
#define PAD 4
#define LDP (HD + PAD)     // 68 floats -> breaks 256B-row bank conflicts

__global__ __launch_bounds__(256) void attn_kernel(
    const float* __restrict__ Q, const float* __restrict__ K,
    const float* __restrict__ V, float* __restrict__ O)
{
    const int bid = blockIdx.x;                  // b*512 + h*32 + qb
    const int qb  = bid & 31;
    const int h   = (bid >> 5) & 15;
    const int b   = bid >> 9;
    const size_t base = (size_t)b * SS * DD + (size_t)h * HD;

    __shared__ float Qs[QB][LDP];
    __shared__ float Ks[KBL][LDP];
    __shared__ float Vs[KBL][LDP];
    __shared__ float Ss[QB][KBL];
    __shared__ float accS[QB][LDP];
    __shared__ float mS[QB], lS[QB], scS[QB];

    const int tid = threadIdx.x;
    const float scale = 0.125f;                  // 1/sqrt(64)

    // load Q tile + init
    for (int e = tid; e < QB * HD; e += 256) {
        const int r = e >> 6, d = e & 63;
        Qs[r][d] = Q[base + (size_t)(qb * QB + r) * DD + d];
        accS[r][d] = 0.f;
    }
    if (tid < QB) { mS[tid] = -1e30f; lS[tid] = 0.f; }
    __syncthreads();

    for (int kb = 0; kb < SS / KBL; ++kb) {
        // stage K,V tiles
        for (int e = tid; e < KBL * HD; e += 256) {
            const int r = e >> 6, d = e & 63;
            Ks[r][d] = K[base + (size_t)(kb * KBL + r) * DD + d];
            Vs[r][d] = V[base + (size_t)(kb * KBL + r) * DD + d];
        }
        __syncthreads();

        // scores: each thread computes 4 consecutive-j entries at one i
        {
            const int e0 = tid * 4;
            const int i  = e0 >> 5;
            const int j0 = e0 & 31;
            float s0 = 0.f, s1 = 0.f, s2 = 0.f, s3 = 0.f;
            #pragma unroll
            for (int d = 0; d < HD; d += 4) {
                const float4 q4 = *(const float4*)&Qs[i][d];
                const float4 k0v = *(const float4*)&Ks[j0 + 0][d];
                const float4 k1v = *(const float4*)&Ks[j0 + 1][d];
                const float4 k2v = *(const float4*)&Ks[j0 + 2][d];
                const float4 k3v = *(const float4*)&Ks[j0 + 3][d];
                s0 += q4.x*k0v.x + q4.y*k0v.y + q4.z*k0v.z + q4.w*k0v.w;
                s1 += q4.x*k1v.x + q4.y*k1v.y + q4.z*k1v.z + q4.w*k1v.w;
                s2 += q4.x*k2v.x + q4.y*k2v.y + q4.z*k2v.z + q4.w*k2v.w;
                s3 += q4.x*k3v.x + q4.y*k3v.y + q4.z*k3v.z + q4.w*k3v.w;
            }
            Ss[i][j0 + 0] = s0 * scale;
            Ss[i][j0 + 1] = s1 * scale;
            Ss[i][j0 + 2] = s2 * scale;
            Ss[i][j0 + 3] = s3 * scale;
        }
        __syncthreads();

        // online softmax: 8 consecutive lanes per row
        {
            const int r = tid >> 3;
            const int g = tid & 7;
            float pm = -1e30f;
            for (int j = g; j < KBL; j += 8) pm = fmaxf(pm, Ss[r][j]);
            #pragma unroll
            for (int off = 1; off < 8; off <<= 1) pm = fmaxf(pm, __shfl_xor(pm, off, 64));
            const float mold = mS[r];
            const float mnew = fmaxf(mold, pm);
            const float sc   = __expf(mold - mnew);
            float ps = 0.f;
            for (int j = g; j < KBL; j += 8) {
                const float p = __expf(Ss[r][j] - mnew);
                Ss[r][j] = p;
                ps += p;
            }
            #pragma unroll
            for (int off = 1; off < 8; off <<= 1) ps += __shfl_xor(ps, off, 64);
            if (g == 0) { mS[r] = mnew; lS[r] = lS[r] * sc + ps; scS[r] = sc; }
        }
        __syncthreads();

        // acc[r][d] = acc[r][d]*sc + P[r][:] @ V[:][d]; thread: r=tid>>3, 8 d's
        {
            const int r  = tid >> 3;
            const int d0 = (tid & 7) * 8;
            float a[8];
            const float sc = scS[r];
            #pragma unroll
            for (int i = 0; i < 8; ++i) a[i] = accS[r][d0 + i] * sc;
            for (int j = 0; j < KBL; ++j) {
                const float p = Ss[r][j];
                const float4 v0 = *(const float4*)&Vs[j][d0];
                const float4 v1 = *(const float4*)&Vs[j][d0 + 4];
                a[0] += p * v0.x; a[1] += p * v0.y; a[2] += p * v0.z; a[3] += p * v0.w;
                a[4] += p * v1.x; a[5] += p * v1.y; a[6] += p * v1.z; a[7] += p * v1.w;
            }
            #pragma unroll
            for (int i = 0; i < 8; ++i) accS[r][d0 + i] = a[i];
        }
        __syncthreads();
    }

    // epilogue: O = acc / l
    {
        const int r  = tid >> 3;
        const int d0 = (tid & 7) * 8;
        const float inv = 1.f / lS[r];
        #pragma unroll
        for (int i = 0; i < 8; ++i)
            O[base + (size_t)(qb * QB + r) * DD + d0 + i] = accS[r][d0 + i] * inv;
    }
}

// ---------------------------------------------------------------------------
// LayerNorm: x = H + pic; out = w * (x-mean)/sqrt(var+eps) + b. Block per row.
// ---------------------------------------------------------------------------
__global__ __launch_bounds__(256) void ln_kernel(
    const float* __restrict__ Hs, const float* __restrict__ P,
    const float* __restrict__ w, const float* __restrict__ bshift,
    float* __restrict__ out)
{
    const int row = blockIdx.x;
    const int tid = threadIdx.x;
    const size_t off = (size_t)row * DD;

    float x[4];
    float s = 0.f;
    #pragma unroll
    for (int i = 0; i < 4; ++i) {
        const int c = tid + i * 256;
        x[i] = Hs[off + c] + P[off + c];
        s += x[i];
    }
    #pragma unroll
    for (int o = 32; o >= 1; o >>= 1) s += __shfl_xor(s, o, 64);

    __shared__ float r1[4], r2[4];
    const int wid = tid >> 6;
    if ((tid & 63) == 0) r1[wid] = s;
    __syncthreads();
    const float mean = (r1[0] + r1[1] + r1[2] + r1[3]) * (1.f / (float)DD);

    float d2 = 0.f;
    #pragma unroll
    for (int i = 0; i < 4; ++i) {
        const float d = x[i] - mean;
        d2 += d * d;
    }
    #pragma unroll
    for (int o = 32; o >= 1; o >>= 1) d2 += __shfl_xor(d2, o, 64);
    if ((tid & 63) == 0) r2[wid] = d2;
    __syncthreads();
    const float var = (r2[0] + r2[1] + r2[2] + r2[3]) * (1.f / (float)DD);
    const float inv = rsqrtf(var + LN_EPS);

    #pragma unroll
    for (int i = 0; i < 4; ++i) {
        const int c = tid + i * 256;
        out[off + c] = w[c] * ((x[i] - mean) * inv) + bshift[c];
    }
}

// ---------------------------------------------------------------------------
extern "C" void kernel_launch(void* const* d_in, const int* in_sizes, int n_in,
                              void* d_out, int out_size, void* d_ws, size_t ws_size,
                              hipStream_t stream)
{
    const float* eeg = (const float*)d_in[0];
    const float* pic = (const float*)d_in[1];
    const float* Wk  = (const float*)d_in[2];
    const float* bk  = (const float*)d_in[3];
    const float* Wq  = (const float*)d_in[4];
    const float* bq  = (const float*)d_in[5];
    const float* Wv  = (const float*)d_in[6];
    const float* bv  = (const float*)d_in[7];
    const float* Wd  = (const float*)d_in[8];
    const float* bd  = (const float*)d_in[9];
    const float* lnw = (const float*)d_in[10];
    const float* lnb = (const float*)d_in[11];
    float* out = (float*)d_out;

    const size_t NEL = (size_t)MM * DD;          // 4M elements
    float* Kbuf = (float*)d_ws;
    float* Qbuf = Kbuf + NEL;
    float* Vbuf = Qbuf + NEL;
    float* Cbuf = Vbuf + NEL;                    // total 64 MB fp32

    dim3 gg(MM / TM, DD / TN);                   // (64, 16)

    gemm_bias<<<gg, 256, 0, stream>>>(eeg, Wk, bk, Kbuf);
    gemm_bias<<<gg, 256, 0, stream>>>(pic, Wq, bq, Qbuf);
    gemm_bias<<<gg, 256, 0, stream>>>(pic, Wv, bv, Vbuf);

    attn_kernel<<<BB * HH * (SS / QB), 256, 0, stream>>>(Qbuf, Kbuf, Vbuf, Cbuf);

    gemm_bias<<<gg, 256, 0, stream>>>(Cbuf, Wd, bd, Qbuf);   // H reuses Qbuf

    ln_kernel<<<MM, 256, 0, stream>>>(Qbuf, pic, lnw, lnb, out);
}

// Round 2
// 171.596 us; speedup vs baseline: 6.4186x; 6.4186x over previous
//
#include <hip/hip_runtime.h>
#include <hip/hip_bf16.h>

// B=4, S=1024, D=1024, H=16, HD=64
#define BB 4
#define SS 1024
#define DD 1024
#define HH 16
#define HD 64
#define MM (BB * SS)
#define LN_EPS 1e-12f

typedef unsigned short u16;
typedef __attribute__((ext_vector_type(8))) short bf16x8;
typedef __attribute__((ext_vector_type(4))) float f32x4;
typedef __attribute__((ext_vector_type(4))) unsigned short u16x4;
typedef __attribute__((ext_vector_type(8))) unsigned short u16x8;

// ---- helpers ---------------------------------------------------------------
__device__ __forceinline__ u16 f2bf(float f) {           // RNE f32->bf16
    unsigned u; __builtin_memcpy(&u, &f, 4);
    unsigned r = (u + 0x7fffu + ((u >> 16) & 1u)) >> 16;
    return (u16)r;
}
__device__ __forceinline__ float bf2f(u16 u) {
    unsigned v = ((unsigned)u) << 16;
    float f; __builtin_memcpy(&f, &v, 4); return f;
}

typedef const __attribute__((address_space(1))) unsigned int* gas1_t;
typedef __attribute__((address_space(3))) unsigned int* las3_t;
__device__ __forceinline__ void gload16(const void* g, void* s) {
    // async global->LDS, 16B per lane; LDS dest = wave-uniform base + lane*16
    __builtin_amdgcn_global_load_lds((gas1_t)g, (las3_t)s, 16, 0, 0);
}

// ---- converters ------------------------------------------------------------
__global__ __launch_bounds__(256) void conv_bf16(const float* __restrict__ in,
                                                 u16* __restrict__ out) {
    size_t i = ((size_t)blockIdx.x * 256 + threadIdx.x) * 8;
    float4 a = *(const float4*)(in + i);
    float4 b = *(const float4*)(in + i + 4);
    u16x8 o;
    o[0]=f2bf(a.x); o[1]=f2bf(a.y); o[2]=f2bf(a.z); o[3]=f2bf(a.w);
    o[4]=f2bf(b.x); o[5]=f2bf(b.y); o[6]=f2bf(b.z); o[7]=f2bf(b.w);
    *(u16x8*)(out + i) = o;
}

// W [K][N] f32 -> Wt [N][K] bf16 (64x64 tiles via LDS)
__global__ __launch_bounds__(256) void transpose_w(const float* __restrict__ W,
                                                   u16* __restrict__ Wt) {
    __shared__ float Ls[64][65];
    const int t = threadIdx.x;
    const int k0 = blockIdx.x * 64, n0 = blockIdx.y * 64;
    #pragma unroll
    for (int i = 0; i < 4; ++i) {
        int r = (t >> 4) + i * 16, c = (t & 15) * 4;
        float4 v = *(const float4*)&W[(size_t)(k0 + r) * DD + n0 + c];
        Ls[r][c] = v.x; Ls[r][c+1] = v.y; Ls[r][c+2] = v.z; Ls[r][c+3] = v.w;
    }
    __syncthreads();
    #pragma unroll
    for (int i = 0; i < 2; ++i) {
        int n = (t >> 3) + i * 32, kc = (t & 7) * 8;
        u16x8 o;
        #pragma unroll
        for (int j = 0; j < 8; ++j) o[j] = f2bf(Ls[kc + j][n]);
        *(u16x8*)&Wt[(size_t)(n0 + n) * DD + k0 + kc] = o;
    }
}

// ---- MFMA GEMM: C[M,N] = A[M,K] @ Bt[N,K]^T + bias, all bf16 in, bf16 out --
// tile 128m x 64n, BK=64, 256 thr (4 waves as 2x2), swizzled LDS (rule #21)
__global__ __launch_bounds__(256) void gemm_mfma(
    const u16* __restrict__ A, const u16* __restrict__ Bt,
    const float* __restrict__ bias, u16* __restrict__ C)
{
    const int tid = threadIdx.x;
    const int w = tid >> 6, l = tid & 63, g = l >> 4, lr = l & 15;
    const int wm = w >> 1, wn = w & 1;
    const int bm = blockIdx.x * 128, bn = blockIdx.y * 64;

    __shared__ u16 As[128 * 64];   // 128 rows x 64 bf16 (128B rows), swizzled
    __shared__ u16 Bs[64 * 64];    // 64 rows(n) x 64 bf16, swizzled

    f32x4 acc[4][2];
    #pragma unroll
    for (int mi = 0; mi < 4; ++mi)
        #pragma unroll
        for (int ni = 0; ni < 2; ++ni) {
            f32x4 z = {0.f, 0.f, 0.f, 0.f};
            acc[mi][ni] = z;
        }

    for (int k0 = 0; k0 < DD; k0 += 64) {
        // stage A: 1024 16B-chunks (4 rounds), pre-swizzled global source
        #pragma unroll
        for (int rr = 0; rr < 4; ++rr) {
            int Cc = rr * 256 + tid;
            int row = Cc >> 3, s = Cc & 7, gc = s ^ (row & 7);
            gload16(A + (size_t)(bm + row) * DD + k0 + gc * 8,
                    As + (rr * 256 + w * 64) * 8);
        }
        // stage Bt: 512 chunks (2 rounds)
        #pragma unroll
        for (int rr = 0; rr < 2; ++rr) {
            int Cc = rr * 256 + tid;
            int row = Cc >> 3, s = Cc & 7, gc = s ^ (row & 7);
            gload16(Bt + (size_t)(bn + row) * DD + k0 + gc * 8,
                    Bs + (rr * 256 + w * 64) * 8);
        }
        __syncthreads();

        #pragma unroll
        for (int kh = 0; kh < 2; ++kh) {
            bf16x8 af[4], bfr[2];
            #pragma unroll
            for (int mi = 0; mi < 4; ++mi) {
                int row = wm * 64 + mi * 16 + lr;
                af[mi] = *(const bf16x8*)((const char*)As + row * 128 +
                                          (((kh * 4 + g) ^ (l & 7))) * 16);
            }
            #pragma unroll
            for (int ni = 0; ni < 2; ++ni) {
                int row = wn * 32 + ni * 16 + lr;
                bfr[ni] = *(const bf16x8*)((const char*)Bs + row * 128 +
                                           (((kh * 4 + g) ^ (l & 7))) * 16);
            }
            #pragma unroll
            for (int mi = 0; mi < 4; ++mi)
                #pragma unroll
                for (int ni = 0; ni < 2; ++ni)
                    acc[mi][ni] = __builtin_amdgcn_mfma_f32_16x16x32_bf16(
                        af[mi], bfr[ni], acc[mi][ni], 0, 0, 0);
        }
        __syncthreads();
    }

    float bv[2];
    bv[0] = bias[bn + wn * 32 + lr];
    bv[1] = bias[bn + wn * 32 + 16 + lr];
    #pragma unroll
    for (int mi = 0; mi < 4; ++mi)
        #pragma unroll
        for (int ni = 0; ni < 2; ++ni)
            #pragma unroll
            for (int r = 0; r < 4; ++r) {
                int row = bm + wm * 64 + mi * 16 + g * 4 + r;
                int col = bn + wn * 32 + ni * 16 + lr;
                C[(size_t)row * DD + col] = f2bf(acc[mi][ni][r] + bv[ni]);
            }
}

// ---- MFMA flash attention --------------------------------------------------
// block = 256 thr (4 waves), handles 64 q-rows of one (b,h). KV step = 32.
// wave w owns q rows w*16..w*16+15. Swapped QK^T -> per-lane q column.
__global__ __launch_bounds__(256) void attn_mfma(
    const u16* __restrict__ Q, const u16* __restrict__ K,
    const u16* __restrict__ V, u16* __restrict__ O)
{
    const int tid = threadIdx.x;
    const int w = tid >> 6, l = tid & 63, g = l >> 4, lr = l & 15;
    const int bid = blockIdx.x;
    const int qb = bid & 15, h = (bid >> 4) & 15, b = bid >> 8;
    const size_t qrow0 = (size_t)b * SS + qb * 64;
    const size_t kvrow0 = (size_t)b * SS;
    const int hc = h * HD;

    __shared__ u16 Qs[64 * 64];      // 8KB, swizzled 128B rows
    __shared__ u16 Ks[32 * 64];      // 4KB, swizzled
    __shared__ u16 Vt[64 * 40];      // V^T padded: d rows x 40 (80B)
    __shared__ u16 Ps[4][16 * 40];   // per-wave P: q rows x 40 (80B)

    // stage Q (512 chunks, swizzled source)
    #pragma unroll
    for (int rr = 0; rr < 2; ++rr) {
        int Cc = rr * 256 + tid;
        int row = Cc >> 3, s = Cc & 7, gc = s ^ (row & 7);
        gload16(Q + (qrow0 + row) * DD + hc + gc * 8,
                Qs + (rr * 256 + w * 64) * 8);
    }
    __syncthreads();

    bf16x8 qf[2];
    {
        int row = w * 16 + lr;
        #pragma unroll
        for (int dh = 0; dh < 2; ++dh)
            qf[dh] = *(const bf16x8*)((const char*)Qs + row * 128 +
                                      ((dh * 4 + g) ^ (l & 7)) * 16);
    }

    f32x4 acc[4];
    #pragma unroll
    for (int dt = 0; dt < 4; ++dt) { f32x4 z = {0.f,0.f,0.f,0.f}; acc[dt] = z; }
    float m_run = -1e30f, l_run = 0.f;
    const float SCL = 0.125f * 1.44269504088896341f;   // scale * log2(e)

    for (int kb = 0; kb < SS / 32; ++kb) {
        // stage K (256 chunks via global_load_lds, swizzled source)
        {
            int Cc = tid;
            int row = Cc >> 3, s = Cc & 7, gc = s ^ (row & 7);
            gload16(K + (kvrow0 + kb * 32 + row) * DD + hc + gc * 8,
                    Ks + (w * 64) * 8);
        }
        // stage V^T (transposed elementwise, padded rows)
        {
            int k = tid >> 3, d0 = (tid & 7) * 8;
            const u16* src = V + (kvrow0 + kb * 32 + k) * DD + hc + d0;
            u16x4 v0 = *(const u16x4*)(src);
            u16x4 v1 = *(const u16x4*)(src + 4);
            #pragma unroll
            for (int j = 0; j < 4; ++j) Vt[(d0 + j) * 40 + k] = v0[j];
            #pragma unroll
            for (int j = 0; j < 4; ++j) Vt[(d0 + 4 + j) * 40 + k] = v1[j];
        }
        __syncthreads();

        // QK^T (swapped): st[kt] holds S^T[k=kt*16+g*4+r][q=lr]
        f32x4 st[2];
        #pragma unroll
        for (int kt = 0; kt < 2; ++kt) {
            int row = kt * 16 + lr;
            bf16x8 k0 = *(const bf16x8*)((const char*)Ks + row * 128 +
                                         ((0 + g) ^ (l & 7)) * 16);
            bf16x8 k1 = *(const bf16x8*)((const char*)Ks + row * 128 +
                                         ((4 + g) ^ (l & 7)) * 16);
            f32x4 z = {0.f, 0.f, 0.f, 0.f};
            z = __builtin_amdgcn_mfma_f32_16x16x32_bf16(k0, qf[0], z, 0, 0, 0);
            z = __builtin_amdgcn_mfma_f32_16x16x32_bf16(k1, qf[1], z, 0, 0, 0);
            st[kt] = z;
        }

        // online softmax in log2 domain (per-lane 8 vals, reduce over xor16/32)
        float sv[8], p[8];
        float tmax = -1e30f;
        #pragma unroll
        for (int kt = 0; kt < 2; ++kt)
            #pragma unroll
            for (int r = 0; r < 4; ++r) {
                float x = st[kt][r] * SCL;
                sv[kt * 4 + r] = x;
                tmax = fmaxf(tmax, x);
            }
        tmax = fmaxf(tmax, __shfl_xor(tmax, 16));
        tmax = fmaxf(tmax, __shfl_xor(tmax, 32));
        float m_new = fmaxf(m_run, tmax);
        float sc_old = exp2f(m_run - m_new);
        float ps = 0.f;
        #pragma unroll
        for (int i = 0; i < 8; ++i) { p[i] = exp2f(sv[i] - m_new); ps += p[i]; }
        ps += __shfl_xor(ps, 16);
        ps += __shfl_xor(ps, 32);
        l_run = l_run * sc_old + ps;
        m_run = m_new;

        // write P (bf16) to per-wave LDS: row q=lr, k = g*4+r (+16 for kt=1)
        {
            u16x4 h0, h1;
            #pragma unroll
            for (int j = 0; j < 4; ++j) { h0[j] = f2bf(p[j]); h1[j] = f2bf(p[4 + j]); }
            char* base = (char*)&Ps[w][0] + lr * 80 + g * 8;
            *(u16x4*)(base) = h0;
            *(u16x4*)(base + 32) = h1;
        }

        // rescale ctx accumulators (q = g*4+r in C/D layout)
        float scq[4];
        #pragma unroll
        for (int r = 0; r < 4; ++r) scq[r] = __shfl(sc_old, g * 4 + r);
        #pragma unroll
        for (int dt = 0; dt < 4; ++dt)
            #pragma unroll
            for (int r = 0; r < 4; ++r) acc[dt][r] *= scq[r];

        // PV: ctx[q][d] += P[q][k] @ V[k][d]
        {
            bf16x8 pf = *(const bf16x8*)((const char*)&Ps[w][0] + lr * 80 + g * 16);
            #pragma unroll
            for (int dt = 0; dt < 4; ++dt) {
                bf16x8 vf = *(const bf16x8*)((const char*)Vt +
                                             (dt * 16 + lr) * 80 + g * 16);
                acc[dt] = __builtin_amdgcn_mfma_f32_16x16x32_bf16(pf, vf, acc[dt], 0, 0, 0);
            }
        }
        __syncthreads();
    }

    // epilogue: divide by l, store bf16
    float invl[4];
    #pragma unroll
    for (int r = 0; r < 4; ++r) invl[r] = 1.f / __shfl(l_run, g * 4 + r);
    #pragma unroll
    for (int dt = 0; dt < 4; ++dt)
        #pragma unroll
        for (int r = 0; r < 4; ++r) {
            size_t row = qrow0 + w * 16 + g * 4 + r;
            O[row * DD + hc + dt * 16 + lr] = f2bf(acc[dt][r] * invl[r]);
        }
}

// ---- residual + LayerNorm --------------------------------------------------
__global__ __launch_bounds__(256) void ln_kernel(
    const u16* __restrict__ Hs, const float* __restrict__ P,
    const float* __restrict__ w, const float* __restrict__ bshift,
    float* __restrict__ out)
{
    const int row = blockIdx.x;
    const int tid = threadIdx.x;
    const size_t off = (size_t)row * DD;
    const int c0 = tid * 4;

    u16x4 h4 = *(const u16x4*)&Hs[off + c0];
    float4 p4 = *(const float4*)&P[off + c0];
    float x[4];
    x[0] = bf2f(h4[0]) + p4.x; x[1] = bf2f(h4[1]) + p4.y;
    x[2] = bf2f(h4[2]) + p4.z; x[3] = bf2f(h4[3]) + p4.w;

    float s = x[0] + x[1] + x[2] + x[3];
    #pragma unroll
    for (int o = 32; o >= 1; o >>= 1) s += __shfl_xor(s, o, 64);

    __shared__ float r1[4], r2[4];
    const int wid = tid >> 6;
    if ((tid & 63) == 0) r1[wid] = s;
    __syncthreads();
    const float mean = (r1[0] + r1[1] + r1[2] + r1[3]) * (1.f / (float)DD);

    float d2 = 0.f;
    #pragma unroll
    for (int i = 0; i < 4; ++i) { float d = x[i] - mean; d2 += d * d; }
    #pragma unroll
    for (int o = 32; o >= 1; o >>= 1) d2 += __shfl_xor(d2, o, 64);
    if ((tid & 63) == 0) r2[wid] = d2;
    __syncthreads();
    const float var = (r2[0] + r2[1] + r2[2] + r2[3]) * (1.f / (float)DD);
    const float inv = rsqrtf(var + LN_EPS);

    float4 o4;
    o4.x = w[c0 + 0] * ((x[0] - mean) * inv) + bshift[c0 + 0];
    o4.y = w[c0 + 1] * ((x[1] - mean) * inv) + bshift[c0 + 1];
    o4.z = w[c0 + 2] * ((x[2] - mean) * inv) + bshift[c0 + 2];
    o4.w = w[c0 + 3] * ((x[3] - mean) * inv) + bshift[c0 + 3];
    *(float4*)&out[off + c0] = o4;
}

// ---------------------------------------------------------------------------
extern "C" void kernel_launch(void* const* d_in, const int* in_sizes, int n_in,
                              void* d_out, int out_size, void* d_ws, size_t ws_size,
                              hipStream_t stream)
{
    const float* eeg = (const float*)d_in[0];
    const float* pic = (const float*)d_in[1];
    const float* Wk  = (const float*)d_in[2];
    const float* bk  = (const float*)d_in[3];
    const float* Wq  = (const float*)d_in[4];
    const float* bq  = (const float*)d_in[5];
    const float* Wv  = (const float*)d_in[6];
    const float* bv  = (const float*)d_in[7];
    const float* Wd  = (const float*)d_in[8];
    const float* bd  = (const float*)d_in[9];
    const float* lnw = (const float*)d_in[10];
    const float* lnb = (const float*)d_in[11];
    float* out = (float*)d_out;

    u16* ws = (u16*)d_ws;
    const size_t M4 = (size_t)1 << 22;   // 4M elems
    u16* Ae  = ws;                        // eeg bf16 [M][D]
    u16* Ap  = ws + M4;                   // pic bf16
    u16* WtK = ws + 2 * M4;               // W^T bf16 [N][K], 1M each
    u16* WtQ = WtK + (1u << 20);
    u16* WtV = WtQ + (1u << 20);
    u16* WtD = WtV + (1u << 20);
    u16* Kb  = ws + 3 * M4;
    u16* Qb  = ws + 4 * M4;
    u16* Vb  = ws + 5 * M4;
    u16* Cb  = ws + 6 * M4;
    u16* Hb  = ws + 7 * M4;

    conv_bf16<<<2048, 256, 0, stream>>>(eeg, Ae);
    conv_bf16<<<2048, 256, 0, stream>>>(pic, Ap);
    transpose_w<<<dim3(16, 16), 256, 0, stream>>>(Wk, WtK);
    transpose_w<<<dim3(16, 16), 256, 0, stream>>>(Wq, WtQ);
    transpose_w<<<dim3(16, 16), 256, 0, stream>>>(Wv, WtV);
    transpose_w<<<dim3(16, 16), 256, 0, stream>>>(Wd, WtD);

    dim3 gg(MM / 128, DD / 64);   // (32, 16)
    gemm_mfma<<<gg, 256, 0, stream>>>(Ae, WtK, bk, Kb);
    gemm_mfma<<<gg, 256, 0, stream>>>(Ap, WtQ, bq, Qb);
    gemm_mfma<<<gg, 256, 0, stream>>>(Ap, WtV, bv, Vb);

    attn_mfma<<<BB * HH * (SS / 64), 256, 0, stream>>>(Qb, Kb, Vb, Cb);

    gemm_mfma<<<gg, 256, 0, stream>>>(Cb, WtD, bd, Hb);

    ln_kernel<<<MM, 256, 0, stream>>>(Hb, pic, lnw, lnb, out);
}

// Round 3
// 122.108 us; speedup vs baseline: 9.0199x; 1.4053x over previous
//
#include <hip/hip_runtime.h>
#include <hip/hip_bf16.h>

// B=4, S=1024, D=1024, H=16, HD=64
#define BB 4
#define SS 1024
#define DD 1024
#define HH 16
#define HD 64
#define MM (BB * SS)
#define LN_EPS 1e-12f

typedef unsigned short u16;
typedef __attribute__((ext_vector_type(8))) short bf16x8;
typedef __attribute__((ext_vector_type(4))) float f32x4;
typedef __attribute__((ext_vector_type(4))) unsigned short u16x4;
typedef __attribute__((ext_vector_type(8))) unsigned short u16x8;

// ---- helpers ---------------------------------------------------------------
__device__ __forceinline__ u16 f2bf(float f) {           // RNE f32->bf16
    unsigned u; __builtin_memcpy(&u, &f, 4);
    unsigned r = (u + 0x7fffu + ((u >> 16) & 1u)) >> 16;
    return (u16)r;
}
__device__ __forceinline__ float bf2f(u16 u) {
    unsigned v = ((unsigned)u) << 16;
    float f; __builtin_memcpy(&f, &v, 4); return f;
}

typedef const __attribute__((address_space(1))) unsigned int* gas1_t;
typedef __attribute__((address_space(3))) unsigned int* las3_t;
__device__ __forceinline__ void gload16(const void* g, void* s) {
    __builtin_amdgcn_global_load_lds((gas1_t)g, (las3_t)s, 16, 0, 0);
}

// ---- converters (fused: eeg + pic in one dispatch) -------------------------
__global__ __launch_bounds__(256) void conv2_bf16(
    const float* __restrict__ a, const float* __restrict__ c,
    u16* __restrict__ oa, u16* __restrict__ oc)
{
    const float* in = blockIdx.y ? c : a;
    u16* out = blockIdx.y ? oc : oa;
    size_t i = ((size_t)blockIdx.x * 256 + threadIdx.x) * 8;
    float4 x = *(const float4*)(in + i);
    float4 y = *(const float4*)(in + i + 4);
    u16x8 o;
    o[0]=f2bf(x.x); o[1]=f2bf(x.y); o[2]=f2bf(x.z); o[3]=f2bf(x.w);
    o[4]=f2bf(y.x); o[5]=f2bf(y.y); o[6]=f2bf(y.z); o[7]=f2bf(y.w);
    *(u16x8*)(out + i) = o;
}

// ---- all 4 weight transposes in one dispatch: W[K][N] f32 -> Wt[N][K] bf16 -
__global__ __launch_bounds__(256) void transpose_w4(
    const float* __restrict__ W0, const float* __restrict__ W1,
    const float* __restrict__ W2, const float* __restrict__ W3,
    u16* __restrict__ T0, u16* __restrict__ T1,
    u16* __restrict__ T2, u16* __restrict__ T3)
{
    const int z = blockIdx.z;
    const float* W = (z==0)?W0:(z==1)?W1:(z==2)?W2:W3;
    u16* Wt = (z==0)?T0:(z==1)?T1:(z==2)?T2:T3;

    __shared__ float Ls[64][65];
    const int t = threadIdx.x;
    const int k0 = blockIdx.x * 64, n0 = blockIdx.y * 64;
    #pragma unroll
    for (int i = 0; i < 4; ++i) {
        int r = (t >> 4) + i * 16, c = (t & 15) * 4;
        float4 v = *(const float4*)&W[(size_t)(k0 + r) * DD + n0 + c];
        Ls[r][c] = v.x; Ls[r][c+1] = v.y; Ls[r][c+2] = v.z; Ls[r][c+3] = v.w;
    }
    __syncthreads();
    #pragma unroll
    for (int i = 0; i < 2; ++i) {
        int n = (t >> 3) + i * 32, kc = (t & 7) * 8;
        u16x8 o;
        #pragma unroll
        for (int j = 0; j < 8; ++j) o[j] = f2bf(Ls[kc + j][n]);
        *(u16x8*)&Wt[(size_t)(n0 + n) * DD + k0 + kc] = o;
    }
}

// ---- shared MFMA GEMM mainloop: 128m x 64n tile, BK=64, 4 waves (2x2) ------
__device__ __forceinline__ void gemm_mainloop(
    const u16* __restrict__ A, const u16* __restrict__ Bt,
    int bm, int bn, u16* As, u16* Bs, f32x4 (&acc)[4][2])
{
    const int tid = threadIdx.x;
    const int w = tid >> 6, l = tid & 63, g = l >> 4, lr = l & 15;
    const int wm = w >> 1, wn = w & 1;

    for (int k0 = 0; k0 < DD; k0 += 64) {
        #pragma unroll
        for (int rr = 0; rr < 4; ++rr) {
            int Cc = rr * 256 + tid;
            int row = Cc >> 3, s = Cc & 7, gc = s ^ (row & 7);
            gload16(A + (size_t)(bm + row) * DD + k0 + gc * 8,
                    As + (rr * 256 + w * 64) * 8);
        }
        #pragma unroll
        for (int rr = 0; rr < 2; ++rr) {
            int Cc = rr * 256 + tid;
            int row = Cc >> 3, s = Cc & 7, gc = s ^ (row & 7);
            gload16(Bt + (size_t)(bn + row) * DD + k0 + gc * 8,
                    Bs + (rr * 256 + w * 64) * 8);
        }
        __syncthreads();

        #pragma unroll
        for (int kh = 0; kh < 2; ++kh) {
            bf16x8 af[4], bfr[2];
            #pragma unroll
            for (int mi = 0; mi < 4; ++mi) {
                int row = wm * 64 + mi * 16 + lr;
                af[mi] = *(const bf16x8*)((const char*)As + row * 128 +
                                          ((kh * 4 + g) ^ (row & 7)) * 16);
            }
            #pragma unroll
            for (int ni = 0; ni < 2; ++ni) {
                int row = wn * 32 + ni * 16 + lr;
                bfr[ni] = *(const bf16x8*)((const char*)Bs + row * 128 +
                                           ((kh * 4 + g) ^ (row & 7)) * 16);
            }
            #pragma unroll
            for (int mi = 0; mi < 4; ++mi)
                #pragma unroll
                for (int ni = 0; ni < 2; ++ni)
                    acc[mi][ni] = __builtin_amdgcn_mfma_f32_16x16x32_bf16(
                        af[mi], bfr[ni], acc[mi][ni], 0, 0, 0);
        }
        __syncthreads();
    }
}

// ---- fused QKV GEMM: grid (32, 48); sel = blockIdx.y>>4 (0=K,1=Q,2=V) ------
// Q output pre-scaled by 0.125*log2(e); V output stored TRANSPOSED VtG[d][m].
__global__ __launch_bounds__(256) void gemm_qkv(
    const u16* __restrict__ Ae, const u16* __restrict__ Ap,
    const u16* __restrict__ Bk, const u16* __restrict__ Bq, const u16* __restrict__ Bv,
    const float* __restrict__ bk, const float* __restrict__ bq, const float* __restrict__ bv,
    u16* __restrict__ Kb, u16* __restrict__ Qb, u16* __restrict__ VtG)
{
    const int sel = blockIdx.y >> 4;
    const int bn = (blockIdx.y & 15) * 64;
    const int bm = blockIdx.x * 128;
    const u16* A  = sel ? Ap : Ae;
    const u16* Bt = (sel == 0) ? Bk : (sel == 1) ? Bq : Bv;
    const float* bias = (sel == 0) ? bk : (sel == 1) ? bq : bv;
    const float alpha = (sel == 1) ? 0.180336880111120f : 1.0f;  // 0.125*log2e

    __shared__ u16 As[128 * 64];
    __shared__ u16 Bs[64 * 64];

    f32x4 acc[4][2];
    #pragma unroll
    for (int mi = 0; mi < 4; ++mi)
        #pragma unroll
        for (int ni = 0; ni < 2; ++ni) { f32x4 z = {0,0,0,0}; acc[mi][ni] = z; }

    gemm_mainloop(A, Bt, bm, bn, As, Bs, acc);

    const int tid = threadIdx.x;
    const int w = tid >> 6, l = tid & 63, g = l >> 4, lr = l & 15;
    const int wm = w >> 1, wn = w & 1;
    float bvv[2];
    bvv[0] = bias[bn + wn * 32 + lr];
    bvv[1] = bias[bn + wn * 32 + 16 + lr];

    if (sel == 2) {
        #pragma unroll
        for (int mi = 0; mi < 4; ++mi)
            #pragma unroll
            for (int ni = 0; ni < 2; ++ni) {
                int col = bn + wn * 32 + ni * 16 + lr;       // d
                int row0 = bm + wm * 64 + mi * 16 + g * 4;   // m
                u16x4 o;
                #pragma unroll
                for (int r = 0; r < 4; ++r) o[r] = f2bf(acc[mi][ni][r] + bvv[ni]);
                *(u16x4*)&VtG[(size_t)col * MM + row0] = o;
            }
    } else {
        u16* C = sel ? Qb : Kb;
        #pragma unroll
        for (int mi = 0; mi < 4; ++mi)
            #pragma unroll
            for (int ni = 0; ni < 2; ++ni)
                #pragma unroll
                for (int r = 0; r < 4; ++r) {
                    int row = bm + wm * 64 + mi * 16 + g * 4 + r;
                    int col = bn + wn * 32 + ni * 16 + lr;
                    C[(size_t)row * DD + col] = f2bf(alpha * (acc[mi][ni][r] + bvv[ni]));
                }
    }
}

// ---- plain GEMM for ctx @ Wd -----------------------------------------------
__global__ __launch_bounds__(256) void gemm_plain(
    const u16* __restrict__ A, const u16* __restrict__ Bt,
    const float* __restrict__ bias, u16* __restrict__ C)
{
    const int bm = blockIdx.x * 128, bn = blockIdx.y * 64;
    __shared__ u16 As[128 * 64];
    __shared__ u16 Bs[64 * 64];

    f32x4 acc[4][2];
    #pragma unroll
    for (int mi = 0; mi < 4; ++mi)
        #pragma unroll
        for (int ni = 0; ni < 2; ++ni) { f32x4 z = {0,0,0,0}; acc[mi][ni] = z; }

    gemm_mainloop(A, Bt, bm, bn, As, Bs, acc);

    const int tid = threadIdx.x;
    const int w = tid >> 6, l = tid & 63, g = l >> 4, lr = l & 15;
    const int wm = w >> 1, wn = w & 1;
    float bvv[2];
    bvv[0] = bias[bn + wn * 32 + lr];
    bvv[1] = bias[bn + wn * 32 + 16 + lr];
    #pragma unroll
    for (int mi = 0; mi < 4; ++mi)
        #pragma unroll
        for (int ni = 0; ni < 2; ++ni)
            #pragma unroll
            for (int r = 0; r < 4; ++r) {
                int row = bm + wm * 64 + mi * 16 + g * 4 + r;
                int col = bn + wn * 32 + ni * 16 + lr;
                C[(size_t)row * DD + col] = f2bf(acc[mi][ni][r] + bvv[ni]);
            }
}

// ---- MFMA flash attention, KV step 64 --------------------------------------
// block = 256 thr (4 waves), 64 q-rows of one (b,h). wave w: q rows w*16..+15.
// Q pre-scaled by 0.125*log2e -> softmax in log2 domain. V from VtG[d][m].
__global__ __launch_bounds__(256) void attn_mfma(
    const u16* __restrict__ Q, const u16* __restrict__ K,
    const u16* __restrict__ Vt, u16* __restrict__ O)
{
    const int tid = threadIdx.x;
    const int w = tid >> 6, l = tid & 63, g = l >> 4, lr = l & 15;
    int bid = (int)blockIdx.x;
    bid = (bid & 7) * 128 + (bid >> 3);          // XCD-chunked swizzle (1024%8==0)
    const int qb = bid & 15, h = (bid >> 4) & 15, b = bid >> 8;
    const size_t qrow0 = (size_t)b * SS + qb * 64;
    const size_t kv0 = (size_t)b * SS;
    const int hc = h * HD;

    __shared__ __align__(16) u16 Ks[64 * 64];     // 8KB, swizzled 128B rows (k-rows)
    __shared__ __align__(16) u16 Vs[64 * 64];     // 8KB, swizzled (d-rows, keys inner)
    __shared__ __align__(16) u16 Ps[4][16 * 72];  // per-wave P, 144B rows

    // Q fragments straight to registers (once)
    bf16x8 qf[2];
    {
        const u16* qp = Q + (qrow0 + w * 16 + lr) * DD + hc + g * 8;
        qf[0] = *(const bf16x8*)(qp);
        qf[1] = *(const bf16x8*)(qp + 32);
    }

    f32x4 acc[4];
    #pragma unroll
    for (int dt = 0; dt < 4; ++dt) { f32x4 z = {0,0,0,0}; acc[dt] = z; }
    float m_run = -1e30f, l_run = 0.f;

    for (int kb = 0; kb < SS / 64; ++kb) {
        // stage K tile: 64 k-rows x 64 d (512 chunks, 2 rounds)
        #pragma unroll
        for (int rr = 0; rr < 2; ++rr) {
            int Cc = rr * 256 + tid;
            int row = Cc >> 3, s = Cc & 7, gc = s ^ (row & 7);
            gload16(K + (kv0 + kb * 64 + row) * DD + hc + gc * 8,
                    Ks + (rr * 256 + w * 64) * 8);
        }
        // stage V^T tile: 64 d-rows x 64 keys
        #pragma unroll
        for (int rr = 0; rr < 2; ++rr) {
            int Cc = rr * 256 + tid;
            int row = Cc >> 3, s = Cc & 7, gc = s ^ (row & 7);
            gload16(Vt + (size_t)(hc + row) * MM + kv0 + kb * 64 + gc * 8,
                    Vs + (rr * 256 + w * 64) * 8);
        }
        __syncthreads();

        // QK^T (swapped): st[kt][r] = S^T[k = kt*16 + g*4 + r][q = lr] (log2-scaled)
        f32x4 st[4];
        #pragma unroll
        for (int kt = 0; kt < 4; ++kt) {
            int row = kt * 16 + lr;
            const char* rb = (const char*)Ks + row * 128;
            bf16x8 k0 = *(const bf16x8*)(rb + ((0 + g) ^ (row & 7)) * 16);
            bf16x8 k1 = *(const bf16x8*)(rb + ((4 + g) ^ (row & 7)) * 16);
            f32x4 z = {0,0,0,0};
            z = __builtin_amdgcn_mfma_f32_16x16x32_bf16(k0, qf[0], z, 0, 0, 0);
            z = __builtin_amdgcn_mfma_f32_16x16x32_bf16(k1, qf[1], z, 0, 0, 0);
            st[kt] = z;
        }

        // online softmax (log2 domain), defer-max rescale (THR = 8)
        float tmax = -1e30f;
        #pragma unroll
        for (int kt = 0; kt < 4; ++kt)
            #pragma unroll
            for (int r = 0; r < 4; ++r) tmax = fmaxf(tmax, st[kt][r]);
        tmax = fmaxf(tmax, __shfl_xor(tmax, 16));
        tmax = fmaxf(tmax, __shfl_xor(tmax, 32));

        if (!__all(tmax <= m_run + 8.f)) {
            float m_new = fmaxf(m_run, tmax);
            float sc = exp2f(m_run - m_new);
            m_run = m_new;
            l_run *= sc;
            float scq[4];
            #pragma unroll
            for (int r = 0; r < 4; ++r) scq[r] = __shfl(sc, g * 4 + r);
            #pragma unroll
            for (int dt = 0; dt < 4; ++dt)
                #pragma unroll
                for (int r = 0; r < 4; ++r) acc[dt][r] *= scq[r];
        }

        float p[16];
        float ps = 0.f;
        #pragma unroll
        for (int kt = 0; kt < 4; ++kt)
            #pragma unroll
            for (int r = 0; r < 4; ++r) {
                float v = exp2f(st[kt][r] - m_run);
                p[kt * 4 + r] = v;
                ps += v;
            }
        ps += __shfl_xor(ps, 16);
        ps += __shfl_xor(ps, 32);
        l_run += ps;

        // P -> per-wave LDS (row q=lr, 144B stride), bf16
        #pragma unroll
        for (int kt = 0; kt < 4; ++kt) {
            u16x4 h4;
            #pragma unroll
            for (int r = 0; r < 4; ++r) h4[r] = f2bf(p[kt * 4 + r]);
            *(u16x4*)((char*)&Ps[w][0] + lr * 144 + kt * 32 + g * 8) = h4;
        }

        // PV: acc[q][d] += P[q][k] @ V[k][d], k split in two 32-halves
        #pragma unroll
        for (int kh = 0; kh < 2; ++kh) {
            bf16x8 pf = *(const bf16x8*)((const char*)&Ps[w][0] + lr * 144 +
                                         kh * 64 + g * 16);
            #pragma unroll
            for (int dt = 0; dt < 4; ++dt) {
                int row = dt * 16 + lr;
                bf16x8 vf = *(const bf16x8*)((const char*)Vs + row * 128 +
                                             ((kh * 4 + g) ^ (row & 7)) * 16);
                acc[dt] = __builtin_amdgcn_mfma_f32_16x16x32_bf16(pf, vf, acc[dt], 0, 0, 0);
            }
        }
        __syncthreads();
    }

    // epilogue
    float invl[4];
    #pragma unroll
    for (int r = 0; r < 4; ++r) invl[r] = 1.f / __shfl(l_run, g * 4 + r);
    #pragma unroll
    for (int dt = 0; dt < 4; ++dt)
        #pragma unroll
        for (int r = 0; r < 4; ++r) {
            size_t row = qrow0 + w * 16 + g * 4 + r;
            O[row * DD + hc + dt * 16 + lr] = f2bf(acc[dt][r] * invl[r]);
        }
}

// ---- residual + LayerNorm --------------------------------------------------
__global__ __launch_bounds__(256) void ln_kernel(
    const u16* __restrict__ Hs, const float* __restrict__ P,
    const float* __restrict__ w, const float* __restrict__ bshift,
    float* __restrict__ out)
{
    const int row = blockIdx.x;
    const int tid = threadIdx.x;
    const size_t off = (size_t)row * DD;
    const int c0 = tid * 4;

    u16x4 h4 = *(const u16x4*)&Hs[off + c0];
    float4 p4 = *(const float4*)&P[off + c0];
    float x[4];
    x[0] = bf2f(h4[0]) + p4.x; x[1] = bf2f(h4[1]) + p4.y;
    x[2] = bf2f(h4[2]) + p4.z; x[3] = bf2f(h4[3]) + p4.w;

    float s = x[0] + x[1] + x[2] + x[3];
    #pragma unroll
    for (int o = 32; o >= 1; o >>= 1) s += __shfl_xor(s, o, 64);

    __shared__ float r1[4], r2[4];
    const int wid = tid >> 6;
    if ((tid & 63) == 0) r1[wid] = s;
    __syncthreads();
    const float mean = (r1[0] + r1[1] + r1[2] + r1[3]) * (1.f / (float)DD);

    float d2 = 0.f;
    #pragma unroll
    for (int i = 0; i < 4; ++i) { float d = x[i] - mean; d2 += d * d; }
    #pragma unroll
    for (int o = 32; o >= 1; o >>= 1) d2 += __shfl_xor(d2, o, 64);
    if ((tid & 63) == 0) r2[wid] = d2;
    __syncthreads();
    const float var = (r2[0] + r2[1] + r2[2] + r2[3]) * (1.f / (float)DD);
    const float inv = rsqrtf(var + LN_EPS);

    float4 o4;
    o4.x = w[c0 + 0] * ((x[0] - mean) * inv) + bshift[c0 + 0];
    o4.y = w[c0 + 1] * ((x[1] - mean) * inv) + bshift[c0 + 1];
    o4.z = w[c0 + 2] * ((x[2] - mean) * inv) + bshift[c0 + 2];
    o4.w = w[c0 + 3] * ((x[3] - mean) * inv) + bshift[c0 + 3];
    *(float4*)&out[off + c0] = o4;
}

// ---------------------------------------------------------------------------
extern "C" void kernel_launch(void* const* d_in, const int* in_sizes, int n_in,
                              void* d_out, int out_size, void* d_ws, size_t ws_size,
                              hipStream_t stream)
{
    const float* eeg = (const float*)d_in[0];
    const float* pic = (const float*)d_in[1];
    const float* Wk  = (const float*)d_in[2];
    const float* bk  = (const float*)d_in[3];
    const float* Wq  = (const float*)d_in[4];
    const float* bq  = (const float*)d_in[5];
    const float* Wv  = (const float*)d_in[6];
    const float* bv  = (const float*)d_in[7];
    const float* Wd  = (const float*)d_in[8];
    const float* bd  = (const float*)d_in[9];
    const float* lnw = (const float*)d_in[10];
    const float* lnb = (const float*)d_in[11];
    float* out = (float*)d_out;

    u16* ws = (u16*)d_ws;
    const size_t M4 = (size_t)1 << 22;   // 4M elems
    u16* Ae  = ws;                       // eeg bf16 [M][D]
    u16* Ap  = ws + M4;                  // pic bf16
    u16* WtK = ws + 2 * M4;              // W^T bf16 [N][K]
    u16* WtQ = WtK + (1u << 20);
    u16* WtV = WtQ + (1u << 20);
    u16* WtD = WtV + (1u << 20);
    u16* Kb  = ws + 3 * M4;              // K  [M][D]
    u16* Qb  = ws + 4 * M4;              // Q (pre-scaled) [M][D]
    u16* VtG = ws + 5 * M4;              // V^T [D][M]
    u16* Cb  = ws + 6 * M4;              // ctx [M][D]
    u16* Hb  = ws + 7 * M4;              // H   [M][D]

    conv2_bf16<<<dim3(2048, 2), 256, 0, stream>>>(eeg, pic, Ae, Ap);
    transpose_w4<<<dim3(16, 16, 4), 256, 0, stream>>>(Wk, Wq, Wv, Wd,
                                                      WtK, WtQ, WtV, WtD);

    gemm_qkv<<<dim3(32, 48), 256, 0, stream>>>(Ae, Ap, WtK, WtQ, WtV,
                                               bk, bq, bv, Kb, Qb, VtG);

    attn_mfma<<<BB * HH * (SS / 64), 256, 0, stream>>>(Qb, Kb, VtG, Cb);

    gemm_plain<<<dim3(32, 16), 256, 0, stream>>>(Cb, WtD, bd, Hb);

    ln_kernel<<<MM, 256, 0, stream>>>(Hb, pic, lnw, lnb, out);
}